// Round 8
// baseline (5449.899 us; speedup 1.0000x reference)
//
#include <hip/hip_runtime.h>
#include <math.h>

// Problem constants (fixed by the reference)
constexpr int kT = 500000;     // history length
constexpr int kQ = 256;        // feature size
constexpr int kH = 256;        // hidden size
constexpr int kK = 32;         // attn_k
constexpr int kNB1 = 256;      // phase-1 top-k blocks
constexpr int kCHUNK = (kT + kNB1 - 1) / kNB1;  // 1954
constexpr int kNC = kNB1 * kK; // 8192 merge candidates
constexpr int kGruRows = 3 * kH;              // 768
constexpr int kGruBlocks = kGruRows / 4;      // 192

// Flat source layout: qs | qh | hs | hnew  (out[1+i] = flat_src[i])
constexpr long long kA = (long long)kT * kQ;        // 128,000,000  qs end
constexpr long long kB = kA + kQ;                   // 128,000,256  qh end
constexpr long long kC = kB + (long long)kT * kH;   // 256,000,256  hs end
constexpr long long kD = kC + kH;                   // 256,000,512  total flat

constexpr int  kCH    = 8192;                       // floats per LDS chunk (32 KB)
constexpr long long kNCHreal = 31250;               // full chunks in [0, kD)
constexpr long long kTailBase = kNCHreal * (long long)kCH; // 256,000,000

typedef float f4  __attribute__((ext_vector_type(4)));
typedef float f4u __attribute__((ext_vector_type(4), aligned(4)));

__device__ __forceinline__ float dot4(f4 a, f4 b) {
  return a.x * b.x + a.y * b.y + a.z * b.z + a.w * b.w;
}

// Scratch floats: alpha kT | candV kNC | candI kNC | gi 768 | gh 768 | hnew 256
constexpr size_t kScratchFloats = (size_t)kT + 2 * kNC + 2 * kGruRows + kH;

// ---------------------------------------------------------------------------
// PRODUCTION copy: LDS-staged. Reads 32 KB aligned chunks, stores shifted
// data from LDS with aligned 16B stores; partial-line co-writes drop to one
// per 32 KB. out[1+i] = flat[i].
__global__ __launch_bounds__(256) void k_copy_lds(
    const float* __restrict__ qs, const float* __restrict__ hs,
    const float* __restrict__ qh, const float* __restrict__ hnew,
    float* __restrict__ out) {
  __shared__ __align__(16) float lds[kCH];
  const int tid = threadIdx.x;
  for (long long c = blockIdx.x; c < kNCHreal; c += gridDim.x) {
    const long long base = c * kCH;
    if (base + kCH <= kA) {                       // pure qs chunk
      const f4* s = (const f4*)(qs + base);
#pragma unroll
      for (int j = 0; j < 8; ++j)
        ((f4*)lds)[tid + 256 * j] = s[tid + 256 * j];
    } else if (base >= kB && base + kCH <= kC) {  // pure hs chunk
      const f4* s = (const f4*)(hs + (base - kB));
#pragma unroll
      for (int j = 0; j < 8; ++j)
        ((f4*)lds)[tid + 256 * j] = s[tid + 256 * j];
    } else {                                      // 1 boundary chunk
      for (int e = tid; e < kCH; e += 256) {
        long long si = base + e;
        float x;
        if (si < kA)      x = qs[si];
        else if (si < kB) x = qh[si - kA];
        else if (si < kC) x = hs[si - kB];
        else              x = hnew[si - kC];
        lds[e] = x;
      }
    }
    __syncthreads();
    float* ob = out + base;
#pragma unroll
    for (int j = 0; j < 8; ++j) {
      int i = tid + 256 * j;
      if (i < 2047) {
        f4 v;
        v.x = lds[3 + 4 * i]; v.y = lds[4 + 4 * i];
        v.z = lds[5 + 4 * i]; v.w = lds[6 + 4 * i];
        *(f4*)(ob + 4 + 4 * i) = v;               // 16B-aligned store
      }
    }
    if (tid == 0) {
      ob[1] = lds[0]; ob[2] = lds[1]; ob[3] = lds[2];
      ob[kCH] = lds[kCH - 1];
    }
    __syncthreads();
  }
  if (blockIdx.x == 0) {                          // tail flat [kTailBase, kD)
    for (int e = tid; e < (int)(kD - kTailBase); e += 256) {
      long long si = kTailBase + e;
      float x = (si < kC) ? hs[si - kB] : hnew[si - kC];
      out[1 + si] = x;
    }
  }
}

// ---------------------------------------------------------------------------
// CALIBRATION kernels (write to d_ws; run after real work; each > 900us so
// they appear in the top-5 profile rows with their own hbm_gbps).
// (a) aligned flat copy x3
__global__ __launch_bounds__(256) void k_cal_aligned(
    const float* __restrict__ qs, const float* __restrict__ hs,
    float* __restrict__ dst) {
  const long long g = (long long)blockIdx.x * blockDim.x + threadIdx.x;
  const long long stride = (long long)gridDim.x * blockDim.x;
  for (int p = 0; p < 3; ++p)
    for (long long i = g; i < 64000000LL; i += stride) {
      f4 v = (i < 32000000LL) ? ((const f4*)qs)[i]
                              : ((const f4*)hs)[i - 32000000LL];
      ((f4*)dst)[i] = v;
    }
}
// (b) +1-shifted flat copy x3 (replica of the 3.6 TB/s plateau pattern)
__global__ __launch_bounds__(256) void k_cal_shifted(
    const float* __restrict__ qs, const float* __restrict__ hs,
    float* __restrict__ dst) {
  const long long g = (long long)blockIdx.x * blockDim.x + threadIdx.x;
  const long long stride = (long long)gridDim.x * blockDim.x;
  for (int p = 0; p < 3; ++p)
    for (long long i = g; i < 64000000LL; i += stride) {
      f4 v = (i < 32000000LL) ? ((const f4*)qs)[i]
                              : ((const f4*)hs)[i - 32000000LL];
      *(f4u*)(dst + 1 + 4 * i) = v;
    }
}
// (c) read-only x5
__global__ __launch_bounds__(256) void k_cal_read(
    const float* __restrict__ qs, const float* __restrict__ hs,
    float* __restrict__ dst) {
  const long long g = (long long)blockIdx.x * blockDim.x + threadIdx.x;
  const long long stride = (long long)gridDim.x * blockDim.x;
  float acc = 0.f;
  for (int p = 0; p < 5; ++p)
    for (long long i = g; i < 64000000LL; i += stride) {
      f4 v = (i < 32000000LL) ? ((const f4*)qs)[i]
                              : ((const f4*)hs)[i - 32000000LL];
      acc += (v.x + v.y) + (v.z + v.w);
    }
  dst[g] = acc;
}
// (d) LDS-staged shifted copy x3 (the production scheme, isolated)
__global__ __launch_bounds__(256) void k_cal_lds(
    const float* __restrict__ qs, const float* __restrict__ hs,
    float* __restrict__ dst) {
  __shared__ __align__(16) float lds[kCH];
  const int tid = threadIdx.x;
  for (int p = 0; p < 3; ++p) {
    for (long long c = blockIdx.x; c < 31250; c += gridDim.x) {
      const long long base = c * kCH;
      const f4* s = (base + kCH <= kA) ? (const f4*)(qs + base)
                                       : (const f4*)(hs + (base - kA));
#pragma unroll
      for (int j = 0; j < 8; ++j)
        ((f4*)lds)[tid + 256 * j] = s[tid + 256 * j];
      __syncthreads();
      float* ob = dst + base;
#pragma unroll
      for (int j = 0; j < 8; ++j) {
        int i = tid + 256 * j;
        if (i < 2047) {
          f4 v;
          v.x = lds[3 + 4 * i]; v.y = lds[4 + 4 * i];
          v.z = lds[5 + 4 * i]; v.w = lds[6 + 4 * i];
          *(f4*)(ob + 4 + 4 * i) = v;
        }
      }
      if (tid == 0) {
        ob[1] = lds[0]; ob[2] = lds[1]; ob[3] = lds[2];
        ob[kCH] = lds[kCH - 1];
      }
      __syncthreads();
    }
  }
}

// ---------------------------------------------------------------------------
// Read-only alpha matvec, 4 independent rows per wave-iteration.
__global__ __launch_bounds__(256) void k_alpha(
    const float* __restrict__ qs, const float* __restrict__ qh,
    float* __restrict__ alpha) {
  const int lane = threadIdx.x & 63;
  const int wid  = (int)((blockIdx.x * blockDim.x + threadIdx.x) >> 6);
  const int nw   = (int)((gridDim.x * blockDim.x) >> 6);
  const f4 q4 = ((const f4*)qh)[lane];
  int t = wid;
  for (; t + 3 * nw < kT; t += 4 * nw) {
    f4 v0 = ((const f4*)(qs + (size_t)t * kQ))[lane];
    f4 v1 = ((const f4*)(qs + (size_t)(t + nw) * kQ))[lane];
    f4 v2 = ((const f4*)(qs + (size_t)(t + 2 * nw) * kQ))[lane];
    f4 v3 = ((const f4*)(qs + (size_t)(t + 3 * nw) * kQ))[lane];
    float d0 = dot4(v0, q4), d1 = dot4(v1, q4);
    float d2 = dot4(v2, q4), d3 = dot4(v3, q4);
#pragma unroll
    for (int off = 32; off; off >>= 1) {
      d0 += __shfl_xor(d0, off);
      d1 += __shfl_xor(d1, off);
      d2 += __shfl_xor(d2, off);
      d3 += __shfl_xor(d3, off);
    }
    if (lane == 0) {
      alpha[t] = d0; alpha[t + nw] = d1;
      alpha[t + 2 * nw] = d2; alpha[t + 3 * nw] = d3;
    }
  }
  for (; t < kT; t += nw) {
    f4 v = ((const f4*)(qs + (size_t)t * kQ))[lane];
    float d = dot4(v, q4);
#pragma unroll
    for (int off = 32; off; off >>= 1) d += __shfl_xor(d, off);
    if (lane == 0) alpha[t] = d;
  }
}

// ---------------------------------------------------------------------------
// GRU matvecs: one row per wave, 4 waves/block.
__global__ __launch_bounds__(256) void k_gru1(
    const float* __restrict__ Wih, const float* __restrict__ Whh,
    const float* __restrict__ bih, const float* __restrict__ bhh,
    const float* __restrict__ qh, const float* __restrict__ hs,
    const float* __restrict__ score, float* __restrict__ gi,
    float* __restrict__ gh) {
  const int lane = threadIdx.x & 63;
  const int r = blockIdx.x * 4 + (threadIdx.x >> 6);
  const int off = (score[0] >= 0.5f) ? 0 : kQ;  // x = [qh*ge, qh*(1-ge)]
  const float* hprev = hs + (size_t)(kT - 1) * kH;
  f4 q4 = ((const f4*)qh)[lane];
  f4 h4 = ((const f4*)hprev)[lane];
  f4 wi = ((const f4*)(Wih + (size_t)r * (2 * kQ) + off))[lane];
  f4 wh = ((const f4*)(Whh + (size_t)r * kH))[lane];
  float di = dot4(wi, q4);
  float dh = dot4(wh, h4);
#pragma unroll
  for (int o = 32; o; o >>= 1) {
    di += __shfl_xor(di, o);
    dh += __shfl_xor(dh, o);
  }
  if (lane == 0) {
    gi[r] = di + bih[r];
    gh[r] = dh + bhh[r];
  }
}

// GRU gates -> hnew_dst.
__global__ __launch_bounds__(256) void k_gru2(
    const float* __restrict__ gi, const float* __restrict__ gh,
    const float* __restrict__ hs, float* __restrict__ hnew_dst) {
  const int i = threadIdx.x;
  const float* hprev = hs + (size_t)(kT - 1) * kH;
  float rr = 1.f / (1.f + expf(-(gi[i] + gh[i])));
  float z  = 1.f / (1.f + expf(-(gi[kH + i] + gh[kH + i])));
  float n  = tanhf(gi[2 * kH + i] + rr * gh[2 * kH + i]);
  hnew_dst[i] = (1.f - z) * n + z * hprev[i];
}

// ---------------------------------------------------------------------------
// Top-k phase 1.
__global__ __launch_bounds__(256) void k_topk1(
    const float* __restrict__ alpha, float* __restrict__ candV,
    int* __restrict__ candI) {
  __shared__ float sv[kCHUNK];
  __shared__ float rv[4];
  __shared__ int ri[4];
  const int tid = threadIdx.x;
  const int base = blockIdx.x * kCHUNK;
  for (int i = tid; i < kCHUNK; i += 256) {
    int g = base + i;
    sv[i] = (g < kT) ? alpha[g] : -INFINITY;
  }
  __syncthreads();
  for (int k = 0; k < kK; ++k) {
    float bv = -INFINITY; int bi = -1;
    for (int i = tid; i < kCHUNK; i += 256) {
      float v = sv[i];
      if (v > bv) { bv = v; bi = i; }
    }
#pragma unroll
    for (int off = 32; off; off >>= 1) {
      float ov = __shfl_xor(bv, off);
      int   oi = __shfl_xor(bi, off);
      if (ov > bv || (ov == bv && oi != -1 && (bi == -1 || oi < bi))) { bv = ov; bi = oi; }
    }
    if ((tid & 63) == 0) { rv[tid >> 6] = bv; ri[tid >> 6] = bi; }
    __syncthreads();
    if (tid == 0) {
      float fv = rv[0]; int fi = ri[0];
      for (int j = 1; j < 4; ++j)
        if (rv[j] > fv || (rv[j] == fv && ri[j] != -1 && (fi == -1 || ri[j] < fi))) {
          fv = rv[j]; fi = ri[j];
        }
      candV[blockIdx.x * kK + k] = fv;
      candI[blockIdx.x * kK + k] = (fi >= 0) ? (base + fi) : 0;
      if (fi >= 0) sv[fi] = -INFINITY;
    }
    __syncthreads();
  }
}

// Top-k phase 2 + softmax + attention + pred (single block).
__global__ __launch_bounds__(256) void k_attn(
    const float* __restrict__ candV, const int* __restrict__ candI,
    const float* __restrict__ hs, const float* __restrict__ qh,
    const float* __restrict__ Ws, const float* __restrict__ bs,
    float* __restrict__ out) {
  __shared__ float sv[kNC];
  __shared__ float rv[4];
  __shared__ int ri[4];
  __shared__ float topv[kK];
  __shared__ int topi[kK];
  __shared__ float w[kK];
  __shared__ float red[256];
  const int tid = threadIdx.x;
  for (int i = tid; i < kNC; i += 256) sv[i] = candV[i];
  __syncthreads();
  for (int k = 0; k < kK; ++k) {
    float bv = -INFINITY; int bi = -1;
    for (int i = tid; i < kNC; i += 256) {
      float v = sv[i];
      if (v > bv) { bv = v; bi = i; }
    }
#pragma unroll
    for (int off = 32; off; off >>= 1) {
      float ov = __shfl_xor(bv, off);
      int   oi = __shfl_xor(bi, off);
      if (ov > bv || (ov == bv && oi != -1 && (bi == -1 || oi < bi))) { bv = ov; bi = oi; }
    }
    if ((tid & 63) == 0) { rv[tid >> 6] = bv; ri[tid >> 6] = bi; }
    __syncthreads();
    if (tid == 0) {
      float fv = rv[0]; int fi = ri[0];
      for (int j = 1; j < 4; ++j)
        if (rv[j] > fv || (rv[j] == fv && ri[j] != -1 && (fi == -1 || ri[j] < fi))) {
          fv = rv[j]; fi = ri[j];
        }
      topv[k] = fv;
      topi[k] = candI[fi];
      sv[fi] = -INFINITY;
    }
    __syncthreads();
  }
  if (tid == 0) {
    float m = topv[0];
    for (int j = 1; j < kK; ++j) m = fmaxf(m, topv[j]);
    float s = 0.f;
    for (int j = 0; j < kK; ++j) { w[j] = expf(topv[j] - m); s += w[j]; }
    float inv = 1.f / s;
    for (int j = 0; j < kK; ++j) w[j] *= inv;
  }
  __syncthreads();
  float a = 0.f;
#pragma unroll
  for (int j = 0; j < kK; ++j) a += w[j] * hs[(size_t)topi[j] * kH + tid];
  red[tid] = Ws[tid] * qh[tid] + Ws[kQ + tid] * a;
  __syncthreads();
  for (int s = 128; s; s >>= 1) {
    if (tid < s) red[tid] += red[tid + s];
    __syncthreads();
  }
  if (tid == 0) out[0] = red[0] + bs[0];
}

extern "C" void kernel_launch(void* const* d_in, const int* in_sizes, int n_in,
                              void* d_out, int out_size, void* d_ws, size_t ws_size,
                              hipStream_t stream) {
  const float* qh    = (const float*)d_in[0];
  const float* score = (const float*)d_in[1];
  const float* qs    = (const float*)d_in[2];
  const float* hs    = (const float*)d_in[3];
  const float* Wih   = (const float*)d_in[4];
  const float* Whh   = (const float*)d_in[5];
  const float* bih   = (const float*)d_in[6];
  const float* bhh   = (const float*)d_in[7];
  const float* Ws    = (const float*)d_in[8];
  const float* bs    = (const float*)d_in[9];
  float* out = (float*)d_out;

  const bool useWs = ws_size >= kScratchFloats * sizeof(float);
  // Fallback: scratch at start of hs_new output region; all consumers run
  // before k_copy_lds (launched last among real work) overwrites it.
  float* S = useWs ? (float*)d_ws : (out + 1 + (size_t)(kT + 1) * kQ);
  float* alpha = S;                         // kT
  float* candV = S + kT;                    // kNC
  int*   candI = (int*)(candV + kNC);       // kNC
  float* gi    = candV + 2 * kNC;           // 768
  float* gh    = gi + kGruRows;             // 768
  float* hnewS = gh + kGruRows;             // 256
  float* hnew  = useWs ? hnewS : (out + 1 + kC);  // fallback: final row direct

  hipLaunchKernelGGL(k_gru1, dim3(kGruBlocks), dim3(256), 0, stream,
                     Wih, Whh, bih, bhh, qh, hs, score, gi, gh);
  hipLaunchKernelGGL(k_gru2, dim3(1), dim3(256), 0, stream,
                     gi, gh, hs, hnew);
  hipLaunchKernelGGL(k_alpha, dim3(2048), dim3(256), 0, stream,
                     qs, qh, alpha);
  hipLaunchKernelGGL(k_topk1, dim3(kNB1), dim3(256), 0, stream,
                     alpha, candV, candI);
  hipLaunchKernelGGL(k_attn, dim3(1), dim3(256), 0, stream,
                     candV, candI, hs, qh, Ws, bs, out);
  hipLaunchKernelGGL(k_copy_lds, dim3(2048), dim3(256), 0, stream,
                     qs, hs, qh, hnew, out);

  // Calibration dispatches (profiling instrumentation; deterministic writes
  // into d_ws far past the scratch region).
  if (useWs && ws_size >= 1700000000ULL) {
    float* cal = (float*)d_ws + 134217728;  // +512 MB
    hipLaunchKernelGGL(k_cal_aligned, dim3(2048), dim3(256), 0, stream,
                       qs, hs, cal);
    hipLaunchKernelGGL(k_cal_shifted, dim3(2048), dim3(256), 0, stream,
                       qs, hs, cal);
    hipLaunchKernelGGL(k_cal_read, dim3(2048), dim3(256), 0, stream,
                       qs, hs, cal);
    hipLaunchKernelGGL(k_cal_lds, dim3(2048), dim3(256), 0, stream,
                       qs, hs, cal);
  }
}

// Round 9
// 657.666 us; speedup vs baseline: 8.2867x; 8.2867x over previous
//
#include <hip/hip_runtime.h>
#include <math.h>

// Problem constants (fixed by the reference)
constexpr int kT = 500000;     // history length
constexpr int kQ = 256;        // feature size
constexpr int kH = 256;        // hidden size
constexpr int kK = 32;         // attn_k
constexpr int kNB1 = 256;      // phase-1 top-k blocks
constexpr int kCHUNK = (kT + kNB1 - 1) / kNB1;  // 1954
constexpr int kNC = kNB1 * kK; // 8192 merge candidates
constexpr int kGruRows = 3 * kH;              // 768
constexpr int kGruBlocks = kGruRows / 4;      // 192

// Flat source layout: qs | qh | hs | hnew  (out[1+i] = flat_src[i])
constexpr long long kA = (long long)kT * kQ;        // 128,000,000  qs end
constexpr long long kB = kA + kQ;                   // 128,000,256  qh end
constexpr long long kC = kB + (long long)kT * kH;   // 256,000,256  hs end
constexpr long long kD = kC + kH;                   // 256,000,512  total flat

constexpr int  kCH = 4096;                          // floats per LDS chunk (16 KB)
constexpr long long kNCH = 62500;                   // full chunks in [0, 256e6)
constexpr long long kTailBase = kNCH * (long long)kCH;  // 256,000,000

typedef float f4 __attribute__((ext_vector_type(4)));

__device__ __forceinline__ float dot4(f4 a, f4 b) {
  return a.x * b.x + a.y * b.y + a.z * b.z + a.w * b.w;
}

// Scratch floats: alpha kT | candV kNC | candI kNC | gi 768 | gh 768 | hnew 256
constexpr size_t kScratchFloats = (size_t)kT + 2 * kNC + 2 * kGruRows + kH;

// ---------------------------------------------------------------------------
// LDS-staged shifted copy: reads 16 KB aligned chunks into LDS, stores the
// +1-float-shifted data with 16B-ALIGNED dwordx4 stores (the shift is
// absorbed in LDS indexing). Mechanism (R8 counters): misaligned 16B stores
// straddle sectors -> 2x L2 write transactions -> 3.2 TB/s cap; aligned
// stores avoid it. out[1+i] = flat[i], flat = qs | qh | hs | hnew.
__global__ __launch_bounds__(256) void k_copy_lds(
    const float* __restrict__ qs, const float* __restrict__ hs,
    const float* __restrict__ qh, const float* __restrict__ hnew,
    float* __restrict__ out) {
  __shared__ __align__(16) float lds[kCH];
  const int tid = threadIdx.x;
  for (long long c = blockIdx.x; c < kNCH; c += gridDim.x) {
    const long long base = c * kCH;
    if (base + kCH <= kA) {                       // pure qs chunk
      const f4* s = (const f4*)(qs + base);
#pragma unroll
      for (int j = 0; j < 4; ++j)
        ((f4*)lds)[tid + 256 * j] = s[tid + 256 * j];
    } else if (base >= kB && base + kCH <= kC) {  // pure hs chunk
      const f4* s = (const f4*)(hs + (base - kB));
#pragma unroll
      for (int j = 0; j < 4; ++j)
        ((f4*)lds)[tid + 256 * j] = s[tid + 256 * j];
    } else {                                      // the 1 boundary chunk
      for (int e = tid; e < kCH; e += 256) {
        long long si = base + e;
        float x;
        if (si < kA)      x = qs[si];
        else if (si < kB) x = qh[si - kA];
        else if (si < kC) x = hs[si - kB];
        else              x = hnew[si - kC];
        lds[e] = x;
      }
    }
    __syncthreads();
    float* ob = out + base;
#pragma unroll
    for (int j = 0; j < 4; ++j) {
      int i = tid + 256 * j;
      if (i < kCH / 4 - 1) {
        f4 v;
        v.x = lds[3 + 4 * i]; v.y = lds[4 + 4 * i];
        v.z = lds[5 + 4 * i]; v.w = lds[6 + 4 * i];
        *(f4*)(ob + 4 + 4 * i) = v;               // 16B-aligned store
      }
    }
    if (tid == 0) {
      ob[1] = lds[0]; ob[2] = lds[1]; ob[3] = lds[2];
      ob[kCH] = lds[kCH - 1];
    }
    __syncthreads();
  }
  if (blockIdx.x == 0) {                          // tail flat [kTailBase, kD)
    for (int e = tid; e < (int)(kD - kTailBase); e += 256) {
      long long si = kTailBase + e;
      float x = (si < kC) ? hs[si - kB] : hnew[si - kC];
      out[1 + si] = x;
    }
  }
}

// ---------------------------------------------------------------------------
// Read-only alpha matvec, 4 independent rows per wave-iteration.
__global__ __launch_bounds__(256) void k_alpha(
    const float* __restrict__ qs, const float* __restrict__ qh,
    float* __restrict__ alpha) {
  const int lane = threadIdx.x & 63;
  const int wid  = (int)((blockIdx.x * blockDim.x + threadIdx.x) >> 6);
  const int nw   = (int)((gridDim.x * blockDim.x) >> 6);
  const f4 q4 = ((const f4*)qh)[lane];
  int t = wid;
  for (; t + 3 * nw < kT; t += 4 * nw) {
    f4 v0 = ((const f4*)(qs + (size_t)t * kQ))[lane];
    f4 v1 = ((const f4*)(qs + (size_t)(t + nw) * kQ))[lane];
    f4 v2 = ((const f4*)(qs + (size_t)(t + 2 * nw) * kQ))[lane];
    f4 v3 = ((const f4*)(qs + (size_t)(t + 3 * nw) * kQ))[lane];
    float d0 = dot4(v0, q4), d1 = dot4(v1, q4);
    float d2 = dot4(v2, q4), d3 = dot4(v3, q4);
#pragma unroll
    for (int off = 32; off; off >>= 1) {
      d0 += __shfl_xor(d0, off);
      d1 += __shfl_xor(d1, off);
      d2 += __shfl_xor(d2, off);
      d3 += __shfl_xor(d3, off);
    }
    if (lane == 0) {
      alpha[t] = d0; alpha[t + nw] = d1;
      alpha[t + 2 * nw] = d2; alpha[t + 3 * nw] = d3;
    }
  }
  for (; t < kT; t += nw) {
    f4 v = ((const f4*)(qs + (size_t)t * kQ))[lane];
    float d = dot4(v, q4);
#pragma unroll
    for (int off = 32; off; off >>= 1) d += __shfl_xor(d, off);
    if (lane == 0) alpha[t] = d;
  }
}

// ---------------------------------------------------------------------------
// GRU matvecs: one row per wave, 4 waves/block.
__global__ __launch_bounds__(256) void k_gru1(
    const float* __restrict__ Wih, const float* __restrict__ Whh,
    const float* __restrict__ bih, const float* __restrict__ bhh,
    const float* __restrict__ qh, const float* __restrict__ hs,
    const float* __restrict__ score, float* __restrict__ gi,
    float* __restrict__ gh) {
  const int lane = threadIdx.x & 63;
  const int r = blockIdx.x * 4 + (threadIdx.x >> 6);
  const int off = (score[0] >= 0.5f) ? 0 : kQ;  // x = [qh*ge, qh*(1-ge)]
  const float* hprev = hs + (size_t)(kT - 1) * kH;
  f4 q4 = ((const f4*)qh)[lane];
  f4 h4 = ((const f4*)hprev)[lane];
  f4 wi = ((const f4*)(Wih + (size_t)r * (2 * kQ) + off))[lane];
  f4 wh = ((const f4*)(Whh + (size_t)r * kH))[lane];
  float di = dot4(wi, q4);
  float dh = dot4(wh, h4);
#pragma unroll
  for (int o = 32; o; o >>= 1) {
    di += __shfl_xor(di, o);
    dh += __shfl_xor(dh, o);
  }
  if (lane == 0) {
    gi[r] = di + bih[r];
    gh[r] = dh + bhh[r];
  }
}

// GRU gates -> hnew_dst.
__global__ __launch_bounds__(256) void k_gru2(
    const float* __restrict__ gi, const float* __restrict__ gh,
    const float* __restrict__ hs, float* __restrict__ hnew_dst) {
  const int i = threadIdx.x;
  const float* hprev = hs + (size_t)(kT - 1) * kH;
  float rr = 1.f / (1.f + expf(-(gi[i] + gh[i])));
  float z  = 1.f / (1.f + expf(-(gi[kH + i] + gh[kH + i])));
  float n  = tanhf(gi[2 * kH + i] + rr * gh[2 * kH + i]);
  hnew_dst[i] = (1.f - z) * n + z * hprev[i];
}

// ---------------------------------------------------------------------------
// Top-k phase 1: each block extracts its chunk's top-32 from LDS.
__global__ __launch_bounds__(256) void k_topk1(
    const float* __restrict__ alpha, float* __restrict__ candV,
    int* __restrict__ candI) {
  __shared__ float sv[kCHUNK];
  __shared__ float rv[4];
  __shared__ int ri[4];
  const int tid = threadIdx.x;
  const int base = blockIdx.x * kCHUNK;
  for (int i = tid; i < kCHUNK; i += 256) {
    int g = base + i;
    sv[i] = (g < kT) ? alpha[g] : -INFINITY;
  }
  __syncthreads();
  for (int k = 0; k < kK; ++k) {
    float bv = -INFINITY; int bi = -1;
    for (int i = tid; i < kCHUNK; i += 256) {
      float v = sv[i];
      if (v > bv) { bv = v; bi = i; }
    }
#pragma unroll
    for (int off = 32; off; off >>= 1) {
      float ov = __shfl_xor(bv, off);
      int   oi = __shfl_xor(bi, off);
      if (ov > bv || (ov == bv && oi != -1 && (bi == -1 || oi < bi))) { bv = ov; bi = oi; }
    }
    if ((tid & 63) == 0) { rv[tid >> 6] = bv; ri[tid >> 6] = bi; }
    __syncthreads();
    if (tid == 0) {
      float fv = rv[0]; int fi = ri[0];
      for (int j = 1; j < 4; ++j)
        if (rv[j] > fv || (rv[j] == fv && ri[j] != -1 && (fi == -1 || ri[j] < fi))) {
          fv = rv[j]; fi = ri[j];
        }
      candV[blockIdx.x * kK + k] = fv;
      candI[blockIdx.x * kK + k] = (fi >= 0) ? (base + fi) : 0;
      if (fi >= 0) sv[fi] = -INFINITY;
    }
    __syncthreads();
  }
}

// Top-k phase 2 + softmax + attention + pred (single block).
__global__ __launch_bounds__(256) void k_attn(
    const float* __restrict__ candV, const int* __restrict__ candI,
    const float* __restrict__ hs, const float* __restrict__ qh,
    const float* __restrict__ Ws, const float* __restrict__ bs,
    float* __restrict__ out) {
  __shared__ float sv[kNC];
  __shared__ float rv[4];
  __shared__ int ri[4];
  __shared__ float topv[kK];
  __shared__ int topi[kK];
  __shared__ float w[kK];
  __shared__ float red[256];
  const int tid = threadIdx.x;
  for (int i = tid; i < kNC; i += 256) sv[i] = candV[i];
  __syncthreads();
  for (int k = 0; k < kK; ++k) {
    float bv = -INFINITY; int bi = -1;
    for (int i = tid; i < kNC; i += 256) {
      float v = sv[i];
      if (v > bv) { bv = v; bi = i; }
    }
#pragma unroll
    for (int off = 32; off; off >>= 1) {
      float ov = __shfl_xor(bv, off);
      int   oi = __shfl_xor(bi, off);
      if (ov > bv || (ov == bv && oi != -1 && (bi == -1 || oi < bi))) { bv = ov; bi = oi; }
    }
    if ((tid & 63) == 0) { rv[tid >> 6] = bv; ri[tid >> 6] = bi; }
    __syncthreads();
    if (tid == 0) {
      float fv = rv[0]; int fi = ri[0];
      for (int j = 1; j < 4; ++j)
        if (rv[j] > fv || (rv[j] == fv && ri[j] != -1 && (fi == -1 || ri[j] < fi))) {
          fv = rv[j]; fi = ri[j];
        }
      topv[k] = fv;
      topi[k] = candI[fi];
      sv[fi] = -INFINITY;
    }
    __syncthreads();
  }
  if (tid == 0) {
    float m = topv[0];
    for (int j = 1; j < kK; ++j) m = fmaxf(m, topv[j]);
    float s = 0.f;
    for (int j = 0; j < kK; ++j) { w[j] = expf(topv[j] - m); s += w[j]; }
    float inv = 1.f / s;
    for (int j = 0; j < kK; ++j) w[j] *= inv;
  }
  __syncthreads();
  float a = 0.f;
#pragma unroll
  for (int j = 0; j < kK; ++j) a += w[j] * hs[(size_t)topi[j] * kH + tid];
  red[tid] = Ws[tid] * qh[tid] + Ws[kQ + tid] * a;
  __syncthreads();
  for (int s = 128; s; s >>= 1) {
    if (tid < s) red[tid] += red[tid + s];
    __syncthreads();
  }
  if (tid == 0) out[0] = red[0] + bs[0];
}

extern "C" void kernel_launch(void* const* d_in, const int* in_sizes, int n_in,
                              void* d_out, int out_size, void* d_ws, size_t ws_size,
                              hipStream_t stream) {
  const float* qh    = (const float*)d_in[0];
  const float* score = (const float*)d_in[1];
  const float* qs    = (const float*)d_in[2];
  const float* hs    = (const float*)d_in[3];
  const float* Wih   = (const float*)d_in[4];
  const float* Whh   = (const float*)d_in[5];
  const float* bih   = (const float*)d_in[6];
  const float* bhh   = (const float*)d_in[7];
  const float* Ws    = (const float*)d_in[8];
  const float* bs    = (const float*)d_in[9];
  float* out = (float*)d_out;

  const bool useWs = ws_size >= kScratchFloats * sizeof(float);
  // Fallback: scratch at start of hs_new output region; all consumers run
  // before k_copy_lds (launched last) overwrites it.
  float* S = useWs ? (float*)d_ws : (out + 1 + (size_t)(kT + 1) * kQ);
  float* alpha = S;                         // kT
  float* candV = S + kT;                    // kNC
  int*   candI = (int*)(candV + kNC);       // kNC
  float* gi    = candV + 2 * kNC;           // 768
  float* gh    = gi + kGruRows;             // 768
  float* hnewS = gh + kGruRows;             // 256
  float* hnew  = useWs ? hnewS : (out + 1 + kC);  // fallback: final row direct
                                            // (copy tail self-copies it, no-op)

  hipLaunchKernelGGL(k_gru1, dim3(kGruBlocks), dim3(256), 0, stream,
                     Wih, Whh, bih, bhh, qh, hs, score, gi, gh);
  hipLaunchKernelGGL(k_gru2, dim3(1), dim3(256), 0, stream,
                     gi, gh, hs, hnew);
  hipLaunchKernelGGL(k_alpha, dim3(2048), dim3(256), 0, stream,
                     qs, qh, alpha);
  hipLaunchKernelGGL(k_topk1, dim3(kNB1), dim3(256), 0, stream,
                     alpha, candV, candI);
  hipLaunchKernelGGL(k_attn, dim3(1), dim3(256), 0, stream,
                     candV, candI, hs, qh, Ws, bs, out);
  hipLaunchKernelGGL(k_copy_lds, dim3(2048), dim3(256), 0, stream,
                     qs, hs, qh, hnew, out);
}